// Round 18
// baseline (49.953 us; speedup 1.0000x reference)
//
#include <hip/hip_runtime.h>
#include <math.h>

// MoE router: logits[16384,64] = X[16384,2048] @ W^T, top-2, softmax(2).
// Outputs flat: weights [16384*2] f32, then indices [16384*2] as float.
//
// R15 fused split-K (1 kernel-class structure): 44.6us.
// R17 single kernel, W staged f32 + in-reg RNE fp16 split: 41.1us.
//     Audit: HBM floor 21.3us, LDS 7.7, VALU 5 -> ~25us expected, ~34 seen.
//     Gap = exposed vmcnt+barrier+prologue at 1 block/CU (160KB LDS).
// R18 TWO blocks/CU: TBLK=32, 256 thr (4 waves = 2 kg x 2 tq), NKG=2,
//     NCH=32. LDS 56KB -> 2 blk/CU, grid 512 = 2/CU. Sync stalls of one
//     block hide under compute of the other. LDS 12.8us / VALU 8.5us by
//     arithmetic -- still under the HBM floor, paid for by overlap.
//     vmcnt re-derived: 6 DMA/thr/iter (X2+W4), outstanding 8, certify
//     oldest 6 -> vmcnt(2); tail vmcnt(0); last bare (red aliases XF).

#define NTOK 16384
#define DDIM 2048
#define NEXP 64
#define TBLK 32                    // tokens per block
#define KC   32
#define NKG  2                     // K-slices per block
#define NCH  32                    // chunks per slice (1024/32)

typedef __attribute__((ext_vector_type(8))) _Float16 f16x8;
typedef __attribute__((ext_vector_type(4))) float f32x4;

// LDS layout (dynamic, 57344 B):
//   XF: 3 bufs x 512 float4  @ 0      (24576 B) [buf][kg][32 tok][8 u]
//   WF: 2 bufs x 1024 float4 @ 24576  (32768 B) [buf][kg][64 e][8 u]
//   red: [2][64][33] f32     @ 0      (16896 B) aliased onto XF
#define XF_OFF 0
#define WF_OFF 24576

__device__ static inline void gload_lds16(const void* gsrc, void* ldst) {
    __builtin_amdgcn_global_load_lds(
        (const __attribute__((address_space(1))) void*)gsrc,
        (__attribute__((address_space(3))) void*)ldst, 16, 0, 0);
}

// 2-level RNE fp16 split: x = h + m + r, |r| <= 2^-24 |x| (x-(float)h exact)
__device__ static inline void split2h(float x, _Float16& h, _Float16& m) {
    h = (_Float16)x;
    float r = x - (float)h;
    m = (_Float16)r;
}

__global__ __launch_bounds__(256, 2) void moe_fused_kernel(
    const float* __restrict__ x,      // [NTOK, DDIM] f32
    const float* __restrict__ gw,     // [NEXP, DDIM] f32
    float* __restrict__ out)          // weights then indices
{
    extern __shared__ char smem[];
    float4* XF = (float4*)(smem + XF_OFF);   // unit = 16 B
    float4* WF = (float4*)(smem + WF_OFF);
    float*  red = (float*)smem;              // [2][64][33], aliased

    const int tid  = threadIdx.x;
    const int lane = tid & 63;
    const int w    = tid >> 6;            // wave 0..3
    const int kg   = w >> 1;              // K-slice 0..1
    const int tq   = w & 1;               // token half 0..1
    const int T0   = blockIdx.x * TBLK;

    // fragment read map: lane l -> row fr, k-group fg
    const int fr  = lane & 15;
    const int fg  = lane >> 4;
    const int akey = fr & 7;              // XOR swizzle key (row&7)

    f32x4 acc[4];
#pragma unroll
    for (int n = 0; n < 4; ++n) acc[n] = (f32x4){0.f, 0.f, 0.f, 0.f};

    // ---- staging: interleaved slice mapping, d = (ch*NKG + s)*KC.
    //      X: 512 units (2/thr). W: 1024 units (4/thr).
#define XSTAGE(ch, buf)                                                       \
    {                                                                         \
        _Pragma("unroll")                                                     \
        for (int k = 0; k < 2; ++k) {                                         \
            const int u = tid + k * 256;                                      \
            const int s = u >> 8;                                             \
            const int r = (u >> 3) & 31;                                      \
            const int c = (u & 7) ^ (r & 7);                                  \
            gload_lds16(x + (size_t)(T0 + r) * DDIM + ((ch) * NKG + s) * KC + c * 4, \
                        &XF[(buf) * 512 + u]);                                \
        }                                                                     \
    }
#define WSTAGE(ch, buf)                                                       \
    {                                                                         \
        _Pragma("unroll")                                                     \
        for (int k = 0; k < 4; ++k) {                                         \
            const int u = tid + k * 256;                                      \
            const int s = u >> 9;                                             \
            const int e = (u >> 3) & 63;                                      \
            const int c = (u & 7) ^ (e & 7);                                  \
            gload_lds16(gw + (size_t)e * DDIM + ((ch) * NKG + s) * KC + c * 4,\
                        &WF[(buf) * 1024 + u]);                               \
        }                                                                     \
    }
#define WAIT2 asm volatile("s_waitcnt vmcnt(2)" ::: "memory")
#define WAIT0 asm volatile("s_waitcnt vmcnt(0)" ::: "memory")
#define BAR   __builtin_amdgcn_s_barrier()

    // prologue: X0(2), W0(4) = oldest 6, then X1(2) in flight
    XSTAGE(0, 0); WSTAGE(0, 0); XSTAGE(1, 1);
    WAIT2; BAR;

    for (int ch = 0; ch < NCH; ++ch) {
        const int xb = ch % 3;
        const int wb = ch & 1;
        if (ch + 1 < NCH) WSTAGE(ch + 1, (ch + 1) & 1);
        if (ch + 2 < NCH) XSTAGE(ch + 2, (ch + 2) % 3);

        // A fragment (one 16-token m-tile): 2-level RNE fp16 split in regs
        const float4* Xc = &XF[xb * 512 + kg * 256];
        f16x8 ah, am;
        {
            const int arow = (tq * 16 + fr) * 8;
            float4 a0 = Xc[arow + ((fg * 2 + 0) ^ akey)];
            float4 a1 = Xc[arow + ((fg * 2 + 1) ^ akey)];
            float xf8[8] = {a0.x, a0.y, a0.z, a0.w, a1.x, a1.y, a1.z, a1.w};
#pragma unroll
            for (int j = 0; j < 8; ++j) {
                _Float16 hj, mj;
                split2h(xf8[j], hj, mj);
                ah[j] = hj; am[j] = mj;
            }
        }

        // B fragments: read f32 pairs, split in registers (key e&7 == fr&7)
        const float4* Wc = &WF[wb * 1024 + kg * 512];
#pragma unroll
        for (int n = 0; n < 4; ++n) {
            const int brow = (n * 16 + fr) * 8;
            float4 b0 = Wc[brow + ((fg * 2 + 0) ^ akey)];
            float4 b1 = Wc[brow + ((fg * 2 + 1) ^ akey)];
            float wf8[8] = {b0.x, b0.y, b0.z, b0.w, b1.x, b1.y, b1.z, b1.w};
            f16x8 bh, bm;
#pragma unroll
            for (int j = 0; j < 8; ++j) {
                _Float16 hj, mj;
                split2h(wf8[j], hj, mj);
                bh[j] = hj; bm[j] = mj;
            }
            acc[n] = __builtin_amdgcn_mfma_f32_16x16x32_f16(am, bm, acc[n], 0, 0, 0);
            acc[n] = __builtin_amdgcn_mfma_f32_16x16x32_f16(am, bh, acc[n], 0, 0, 0);
            acc[n] = __builtin_amdgcn_mfma_f32_16x16x32_f16(ah, bm, acc[n], 0, 0, 0);
            acc[n] = __builtin_amdgcn_mfma_f32_16x16x32_f16(ah, bh, acc[n], 0, 0, 0);
        }

        if (ch + 2 < NCH)      { WAIT2; BAR; }
        else if (ch + 1 < NCH) { WAIT0; BAR; }
        else                   { BAR; }      // WAR: red aliases XF
    }
#undef XSTAGE
#undef WSTAGE
#undef WAIT2
#undef WAIT0
#undef BAR

    // ---- epilogue 1: C/D frags -> red[kg][exp][tok] (padded 33) ----
    // C/D: col = fr (expert in n-tile), row = fg*4 + j (token) [m89]
#pragma unroll
    for (int n = 0; n < 4; ++n)
#pragma unroll
        for (int j = 0; j < 4; ++j) {
            const int e = n * 16 + fr;
            const int t = tq * 16 + fg * 4 + j;
            red[kg * 2112 + e * 33 + t] = acc[n][j];
        }
    __syncthreads();

    // ---- epilogue 2: reduce 2 K-slices ascending (owner-only slots) ----
#pragma unroll
    for (int k = 0; k < 8; ++k) {
        const int q = tid + k * 256;
        const int e = q >> 5;
        const int t = q & 31;
        red[e * 33 + t] = red[e * 33 + t] + red[2112 + e * 33 + t];
    }
    __syncthreads();

    // ---- epilogue 3: top-2 + softmax (lane t scans [e][t], stride 33) ----
    if (tid < TBLK) {
        const int t = tid;
        float m1 = -INFINITY, m2 = -INFINITY;
        int i1 = 0, i2 = 0;
        for (int e = 0; e < NEXP; ++e) {
            float v = red[e * 33 + t];
            if (v > m1) {              // strict '>' = lowest index on ties
                m2 = m1; i2 = i1;
                m1 = v;  i1 = e;
            } else if (v > m2) {
                m2 = v;  i2 = e;
            }
        }
        float e2 = expf(m2 - m1);
        float denom = 1.f + e2;
        const int gt = T0 + t;
        out[gt * 2 + 0] = 1.f / denom;
        out[gt * 2 + 1] = e2 / denom;
        out[NTOK * 2 + gt * 2 + 0] = (float)i1;
        out[NTOK * 2 + gt * 2 + 1] = (float)i2;
    }
}

extern "C" void kernel_launch(void* const* d_in, const int* in_sizes, int n_in,
                              void* d_out, int out_size, void* d_ws, size_t ws_size,
                              hipStream_t stream) {
    const float* x  = (const float*)d_in[0];   // [4,4096,2048] f32
    const float* gw = (const float*)d_in[1];   // [64,2048] f32
    float* out = (float*)d_out;
    (void)d_ws; (void)ws_size;

    moe_fused_kernel<<<dim3(NTOK / TBLK), dim3(256), 57344, stream>>>(
        x, gw, out);
}

// Round 19
// 41.501 us; speedup vs baseline: 1.2037x; 1.2037x over previous
//
#include <hip/hip_runtime.h>
#include <math.h>

// MoE router: logits[16384,64] = X[16384,2048] @ W^T, top-2, softmax(2).
// Outputs flat: weights [16384*2] f32, then indices [16384*2] as float.
//
// FINAL (R19 = exact R17 restore, best = 41.1us):
// R14 fp16 4-product (2-level RNE split, Sterbenz-exact residual): 47.6us.
// R15 fused in-block split-K + LDS reduce + inline top-2: 44.6us.
// R16 K-slice interleave: NEUTRAL (DRAM-pattern theory wrong).
// R17 single kernel, W staged raw f32 + in-reg fp16 split: 41.1us.  <-- this
// R18 TBLK=32 for 2 blk/CU: 50us REGRESSION -- W overhead (DMA + LDS reads
//     + split VALU) is fixed per block; halving TBLK doubled it per token.
//     TBLK=64 (grid=256=full CU coverage) is the optimum of this family.
// Structural floor arithmetic: X stream 128MiB @6.3TB/s = 21.3us + prologue
// ~2us + launch ~3-5us => ~27us; residual ~14us = partially-exposed sync at
// 1 blk/CU (160KB LDS), shown irreducible by R16/R18.

#define NTOK 16384
#define DDIM 2048
#define NEXP 64
#define TBLK 64                    // tokens per block
#define KC   32
#define NKG  4                     // K-slices per block
#define NCH  16                    // chunks per slice

typedef __attribute__((ext_vector_type(8))) _Float16 f16x8;
typedef __attribute__((ext_vector_type(4))) float f32x4;

// LDS layout (dynamic, 163840 B):
//   XF: 3 bufs x 2048 float4 @ 0      (98304 B) [buf][kg][64 tok][8 u]
//   WF: 2 bufs x 2048 float4 @ 98304  (65536 B) [buf][kg][64 e][8 u]
//   red: [4][64][65] f32     @ 0      (66560 B) aliased onto XF
#define XF_OFF 0
#define WF_OFF 98304

__device__ static inline void gload_lds16(const void* gsrc, void* ldst) {
    __builtin_amdgcn_global_load_lds(
        (const __attribute__((address_space(1))) void*)gsrc,
        (__attribute__((address_space(3))) void*)ldst, 16, 0, 0);
}

// 2-level RNE fp16 split: x = h + m + r, |r| <= 2^-24 |x| (x-(float)h exact)
__device__ static inline void split2h(float x, _Float16& h, _Float16& m) {
    h = (_Float16)x;
    float r = x - (float)h;
    m = (_Float16)r;
}

// ---- fused: stage X,W f32 -> split in regs -> MFMA fp16x4 -> reduce -> top2
__global__ __launch_bounds__(512, 1) void moe_fused_kernel(
    const float* __restrict__ x,      // [NTOK, DDIM] f32
    const float* __restrict__ gw,     // [NEXP, DDIM] f32
    float* __restrict__ out)          // weights then indices
{
    extern __shared__ char smem[];
    float4* XF = (float4*)(smem + XF_OFF);   // unit = 16 B
    float4* WF = (float4*)(smem + WF_OFF);
    float*  red = (float*)smem;              // [4][64][65], aliased

    const int tid  = threadIdx.x;
    const int lane = tid & 63;
    const int w    = tid >> 6;            // wave 0..7
    const int kg   = w >> 1;              // K-slice 0..3
    const int tq   = w & 1;               // token half 0..1
    const int T0   = blockIdx.x * TBLK;

    // fragment read map: lane l -> row fr, k-group fg
    const int fr  = lane & 15;
    const int fg  = lane >> 4;
    const int akey = fr & 7;              // XOR swizzle key (rows: tok or e)

    f32x4 acc[2][4];
#pragma unroll
    for (int mi = 0; mi < 2; ++mi)
#pragma unroll
        for (int n = 0; n < 4; ++n) acc[mi][n] = (f32x4){0.f, 0.f, 0.f, 0.f};

    // ---- staging: interleaved slice mapping, d = (ch*NKG + s)*KC.
    //      X: 2048 units (4/thr). W: 2048 units (4/thr). Same swizzle form.
#define XSTAGE(ch, buf)                                                       \
    {                                                                         \
        _Pragma("unroll")                                                     \
        for (int k = 0; k < 4; ++k) {                                         \
            const int u = tid + k * 512;                                      \
            const int s = u >> 9;                                             \
            const int r = (u >> 3) & 63;                                      \
            const int c = (u & 7) ^ (r & 7);                                  \
            gload_lds16(x + (size_t)(T0 + r) * DDIM + ((ch) * NKG + s) * KC + c * 4, \
                        &XF[(buf) * 2048 + u]);                               \
        }                                                                     \
    }
#define WSTAGE(ch, buf)                                                       \
    {                                                                         \
        _Pragma("unroll")                                                     \
        for (int k = 0; k < 4; ++k) {                                         \
            const int u = tid + k * 512;                                      \
            const int s = u >> 9;                                             \
            const int e = (u >> 3) & 63;                                      \
            const int c = (u & 7) ^ (e & 7);                                  \
            gload_lds16(gw + (size_t)e * DDIM + ((ch) * NKG + s) * KC + c * 4,\
                        &WF[(buf) * 2048 + u]);                               \
        }                                                                     \
    }
#define WAIT4 asm volatile("s_waitcnt vmcnt(4)" ::: "memory")
#define WAIT0 asm volatile("s_waitcnt vmcnt(0)" ::: "memory")
#define BAR   __builtin_amdgcn_s_barrier()

    // prologue: X0(4), W0(4) = oldest 8, then X1(4) in flight
    XSTAGE(0, 0); WSTAGE(0, 0); XSTAGE(1, 1);
    WAIT4; BAR;

    for (int ch = 0; ch < NCH; ++ch) {
        const int xb = ch % 3;
        const int wb = ch & 1;
        if (ch + 1 < NCH) WSTAGE(ch + 1, (ch + 1) & 1);
        if (ch + 2 < NCH) XSTAGE(ch + 2, (ch + 2) % 3);

        // A fragments: 2-level RNE fp16 split in registers
        const float4* Xc = &XF[xb * 2048 + kg * 512];
        f16x8 ah[2], am[2];
#pragma unroll
        for (int mi = 0; mi < 2; ++mi) {
            const int arow = (tq * 32 + mi * 16 + fr) * 8;
            float4 a0 = Xc[arow + ((fg * 2 + 0) ^ akey)];
            float4 a1 = Xc[arow + ((fg * 2 + 1) ^ akey)];
            float xf8[8] = {a0.x, a0.y, a0.z, a0.w, a1.x, a1.y, a1.z, a1.w};
#pragma unroll
            for (int j = 0; j < 8; ++j) {
                _Float16 hj, mj;
                split2h(xf8[j], hj, mj);
                ah[mi][j] = hj; am[mi][j] = mj;
            }
        }

        // B fragments: read f32 pairs, split in registers (key e&7 == fr&7)
        const float4* Wc = &WF[wb * 2048 + kg * 512];
#pragma unroll
        for (int n = 0; n < 4; ++n) {
            const int brow = (n * 16 + fr) * 8;
            float4 b0 = Wc[brow + ((fg * 2 + 0) ^ akey)];
            float4 b1 = Wc[brow + ((fg * 2 + 1) ^ akey)];
            float wf8[8] = {b0.x, b0.y, b0.z, b0.w, b1.x, b1.y, b1.z, b1.w};
            f16x8 bh, bm;
#pragma unroll
            for (int j = 0; j < 8; ++j) {
                _Float16 hj, mj;
                split2h(wf8[j], hj, mj);
                bh[j] = hj; bm[j] = mj;
            }
#pragma unroll
            for (int mi = 0; mi < 2; ++mi) {
                acc[mi][n] = __builtin_amdgcn_mfma_f32_16x16x32_f16(am[mi], bm, acc[mi][n], 0, 0, 0);
                acc[mi][n] = __builtin_amdgcn_mfma_f32_16x16x32_f16(am[mi], bh, acc[mi][n], 0, 0, 0);
                acc[mi][n] = __builtin_amdgcn_mfma_f32_16x16x32_f16(ah[mi], bm, acc[mi][n], 0, 0, 0);
                acc[mi][n] = __builtin_amdgcn_mfma_f32_16x16x32_f16(ah[mi], bh, acc[mi][n], 0, 0, 0);
            }
        }

        if (ch + 2 < NCH)      { WAIT4; BAR; }
        else if (ch + 1 < NCH) { WAIT0; BAR; }
        else                   { BAR; }      // WAR: red aliases XF
    }
#undef XSTAGE
#undef WSTAGE
#undef WAIT4
#undef WAIT0
#undef BAR

    // ---- epilogue 1: C/D frags -> red[kg][exp][tok] (padded 65) ----
    // C/D: col = fr (expert in n-tile), row = fg*4 + j (token) [m89]
#pragma unroll
    for (int mi = 0; mi < 2; ++mi)
#pragma unroll
        for (int n = 0; n < 4; ++n)
#pragma unroll
            for (int j = 0; j < 4; ++j) {
                const int e = n * 16 + fr;
                const int t = tq * 32 + mi * 16 + fg * 4 + j;
                red[kg * 4160 + e * 65 + t] = acc[mi][n][j];
            }
    __syncthreads();

    // ---- epilogue 2: reduce K-slices ascending (owner-only slots) ----
#pragma unroll
    for (int k = 0; k < 8; ++k) {
        const int q = tid + k * 512;
        const int e = q >> 6;
        const int t = q & 63;
        float s = red[0 * 4160 + e * 65 + t];
#pragma unroll
        for (int sl = 1; sl < NKG; ++sl)
            s += red[sl * 4160 + e * 65 + t];
        red[e * 65 + t] = s;
    }
    __syncthreads();

    // ---- epilogue 3: top-2 + softmax (lane t scans [e][t], conflict-free)
    if (tid < TBLK) {
        const int t = tid;
        float m1 = -INFINITY, m2 = -INFINITY;
        int i1 = 0, i2 = 0;
        for (int e = 0; e < NEXP; ++e) {
            float v = red[e * 65 + t];
            if (v > m1) {              // strict '>' = lowest index on ties
                m2 = m1; i2 = i1;
                m1 = v;  i1 = e;
            } else if (v > m2) {
                m2 = v;  i2 = e;
            }
        }
        float e2 = expf(m2 - m1);
        float denom = 1.f + e2;
        const int gt = T0 + t;
        out[gt * 2 + 0] = 1.f / denom;
        out[gt * 2 + 1] = e2 / denom;
        out[NTOK * 2 + gt * 2 + 0] = (float)i1;
        out[NTOK * 2 + gt * 2 + 1] = (float)i2;
    }
}

extern "C" void kernel_launch(void* const* d_in, const int* in_sizes, int n_in,
                              void* d_out, int out_size, void* d_ws, size_t ws_size,
                              hipStream_t stream) {
    const float* x  = (const float*)d_in[0];   // [4,4096,2048] f32
    const float* gw = (const float*)d_in[1];   // [64,2048] f32
    float* out = (float*)d_out;
    (void)d_ws; (void)ws_size;

    moe_fused_kernel<<<dim3(NTOK / TBLK), dim3(512), 163840, stream>>>(
        x, gw, out);
}